// Round 1
// baseline (2915.500 us; speedup 1.0000x reference)
//
#include <hip/hip_runtime.h>

#define F 128

// ---------------- scatter: deg + ah accumulation over edges ----------------
// 32 threads per edge; each thread handles 4 contiguous floats (float4 gather).
__global__ __launch_bounds__(256) void gcn_scatter(
    const float* __restrict__ h, const int* __restrict__ src,
    const int* __restrict__ dst, float* __restrict__ ah,
    float* __restrict__ deg, int n_edges)
{
    int t  = blockIdx.x * 256 + threadIdx.x;
    int e  = t >> 5;          // edge index
    int f4 = t & 31;          // float4 index within the 128-feature row
    if (e >= n_edges) return;
    int s = src[e];
    int d = dst[e];
    if (f4 == 0) atomicAdd(&deg[d], 1.0f);
    float4 v = ((const float4*)(h + (size_t)s * F))[f4];
    float* dp = ah + (size_t)d * F + f4 * 4;
    atomicAdd(dp + 0, v.x);
    atomicAdd(dp + 1, v.y);
    atomicAdd(dp + 2, v.z);
    atomicAdd(dp + 3, v.w);
}

// ---------------- transform: norm -> matmul+bias -> LayerNorm -> ReLU ------
// Block = 256 threads: j = tid&127 (output column), h2 = tid>>7 (k-half).
// Each thread keeps its 64 W values in registers (loaded once per block).
// Grid-strides over nodes, 1 node per block-iteration. In-place on d_out.
__global__ __launch_bounds__(256) void gcn_transform(
    const float* __restrict__ w, const float* __restrict__ bias,
    const float* __restrict__ gamma, const float* __restrict__ beta,
    const float* __restrict__ deg, float* __restrict__ x /* ah in, out */,
    int n_nodes)
{
    __shared__ float xa[F];        // normalized ah row
    __shared__ float part[2][F];   // k-half partial dots
    __shared__ float wsum[4], wsq[4];

    const int tid = threadIdx.x;
    const int j  = tid & (F - 1);
    const int h2 = tid >> 7;       // 0 or 1 : which half of k

    float wreg[64];
    #pragma unroll
    for (int k = 0; k < 64; ++k)
        wreg[k] = w[(size_t)(h2 * 64 + k) * F + j];

    const float bj  = bias[j];
    const float gj  = gamma[j];
    const float btj = beta[j];

    for (int node = blockIdx.x; node < n_nodes; node += gridDim.x) {
        if (tid < F) {
            float dg = deg[node];
            float nv = dg > 0.0f ? 1.0f / dg : 0.0f;
            xa[tid] = x[(size_t)node * F + tid] * nv;
        }
        __syncthreads();

        float acc = 0.0f;
        #pragma unroll
        for (int k = 0; k < 64; ++k)
            acc = fmaf(xa[h2 * 64 + k], wreg[k], acc);
        part[h2][j] = acc;
        __syncthreads();

        float xv = 0.0f;
        if (h2 == 0) xv = part[0][j] + part[1][j] + bj;

        // wave-level reduce (waves 0,1 hold the real values; 2,3 compute zeros)
        float s = xv, q = xv * xv;
        #pragma unroll
        for (int o = 32; o > 0; o >>= 1) {
            s += __shfl_xor(s, o);
            q += __shfl_xor(q, o);
        }
        if ((tid & 63) == 0) { wsum[tid >> 6] = s; wsq[tid >> 6] = q; }
        __syncthreads();

        if (h2 == 0) {
            float mean = (wsum[0] + wsum[1]) * (1.0f / F);
            float var  = (wsq[0] + wsq[1]) * (1.0f / F) - mean * mean;
            float rstd = rsqrtf(var + 1e-5f);
            float y = (xv - mean) * rstd * gj + btj;
            x[(size_t)node * F + j] = fmaxf(y, 0.0f);
        }
        // next iteration's first __syncthreads orders xa/part rewrites; safe.
    }
}

extern "C" void kernel_launch(void* const* d_in, const int* in_sizes, int n_in,
                              void* d_out, int out_size, void* d_ws, size_t ws_size,
                              hipStream_t stream) {
    const float* h      = (const float*)d_in[0];
    const float* weight = (const float*)d_in[1];
    const float* bias   = (const float*)d_in[2];
    const float* gamma  = (const float*)d_in[3];
    const float* beta   = (const float*)d_in[4];
    const int*   src    = (const int*)d_in[5];
    const int*   dst    = (const int*)d_in[6];

    const int n_nodes = in_sizes[0] / F;
    const int n_edges = in_sizes[5];

    float* ah  = (float*)d_out;   // accumulate ah directly into d_out (N x 128)
    float* deg = (float*)d_ws;    // N floats of scratch

    hipMemsetAsync(d_out, 0, (size_t)n_nodes * F * sizeof(float), stream);
    hipMemsetAsync(d_ws, 0, (size_t)n_nodes * sizeof(float), stream);

    {
        int total = n_edges * 32;
        int blocks = (total + 255) / 256;
        gcn_scatter<<<blocks, 256, 0, stream>>>(h, src, dst, ah, deg, n_edges);
    }
    {
        int blocks = 4096;
        gcn_transform<<<blocks, 256, 0, stream>>>(weight, bias, gamma, beta,
                                                  deg, ah, n_nodes);
    }
}

// Round 2
// 417.640 us; speedup vs baseline: 6.9809x; 6.9809x over previous
//
#include <hip/hip_runtime.h>

#define F 128
#define SCANB 1024

// ---------- CSR build: histogram of dst ----------
__global__ __launch_bounds__(256) void k_hist(const int* __restrict__ dst,
                                              int* __restrict__ deg, int n_edges) {
    int e = blockIdx.x * 256 + threadIdx.x;
    if (e < n_edges) atomicAdd(&deg[dst[e]], 1);
}

// ---------- exclusive scan over deg (3 kernels) ----------
__global__ __launch_bounds__(SCANB) void k_scan_a(const int* __restrict__ deg,
                                                  int* __restrict__ offs,
                                                  int* __restrict__ bsum, int n) {
    __shared__ int tmp[SCANB];
    int i = blockIdx.x * SCANB + threadIdx.x;
    int v = (i < n) ? deg[i] : 0;
    tmp[threadIdx.x] = v;
    __syncthreads();
    for (int off = 1; off < SCANB; off <<= 1) {
        int t = (threadIdx.x >= off) ? tmp[threadIdx.x - off] : 0;
        __syncthreads();
        tmp[threadIdx.x] += t;
        __syncthreads();
    }
    if (i < n) offs[i] = tmp[threadIdx.x] - v;           // exclusive
    if (threadIdx.x == SCANB - 1) bsum[blockIdx.x] = tmp[SCANB - 1];
}

__global__ void k_scan_b(int* bsum, int nb) {
    if (threadIdx.x == 0 && blockIdx.x == 0) {
        int run = 0;
        for (int b = 0; b < nb; ++b) { int t = bsum[b]; bsum[b] = run; run += t; }
    }
}

__global__ __launch_bounds__(SCANB) void k_scan_c(int* __restrict__ offs,
                                                  const int* __restrict__ bsum, int n) {
    int i = blockIdx.x * SCANB + threadIdx.x;
    if (i < n) offs[i] += bsum[blockIdx.x];
}

// ---------- scatter edge src-ids into CSR order ----------
__global__ __launch_bounds__(256) void k_scatter_idx(
    const int* __restrict__ src, const int* __restrict__ dst,
    const int* __restrict__ offs, int* __restrict__ cursor,
    int* __restrict__ esrc, int n_edges) {
    int e = blockIdx.x * 256 + threadIdx.x;
    if (e >= n_edges) return;
    int d = dst[e];
    int pos = offs[d] + atomicAdd(&cursor[d], 1);
    esrc[pos] = src[e];
}

// ---------- gather-sum: one 64-lane wave per node, float2 per lane ----------
__global__ __launch_bounds__(256) void k_gather(
    const float* __restrict__ h, const int* __restrict__ esrc,
    const int* __restrict__ offs, const int* __restrict__ deg,
    float* __restrict__ x, int n_nodes) {
    int t = blockIdx.x * 256 + threadIdx.x;
    int node = t >> 6;
    int lane = t & 63;
    if (node >= n_nodes) return;
    int start = offs[node];
    int dn = deg[node];
    const float2* hp = (const float2*)h;
    float ax = 0.0f, ay = 0.0f;
    int i = 0;
    for (; i + 4 <= dn; i += 4) {
        int s0 = esrc[start + i + 0], s1 = esrc[start + i + 1];
        int s2 = esrc[start + i + 2], s3 = esrc[start + i + 3];
        float2 v0 = hp[(size_t)s0 * 64 + lane];
        float2 v1 = hp[(size_t)s1 * 64 + lane];
        float2 v2 = hp[(size_t)s2 * 64 + lane];
        float2 v3 = hp[(size_t)s3 * 64 + lane];
        ax += (v0.x + v1.x) + (v2.x + v3.x);
        ay += (v0.y + v1.y) + (v2.y + v3.y);
    }
    for (; i < dn; ++i) {
        int s = esrc[start + i];
        float2 v = hp[(size_t)s * 64 + lane];
        ax += v.x; ay += v.y;
    }
    float nv = dn > 0 ? 1.0f / (float)dn : 0.0f;
    ((float2*)x)[(size_t)node * 64 + lane] = make_float2(ax * nv, ay * nv);
}

// ---------- fallback scatter (float atomics) if ws too small ----------
__global__ __launch_bounds__(256) void gcn_scatter_atomic(
    const float* __restrict__ h, const int* __restrict__ src,
    const int* __restrict__ dst, float* __restrict__ ah,
    float* __restrict__ degf, int n_edges) {
    int t  = blockIdx.x * 256 + threadIdx.x;
    int e  = t >> 5;
    int f4 = t & 31;
    if (e >= n_edges) return;
    int s = src[e];
    int d = dst[e];
    if (f4 == 0) atomicAdd(&degf[d], 1.0f);
    float4 v = ((const float4*)(h + (size_t)s * F))[f4];
    float* dp = ah + (size_t)d * F + f4 * 4;
    atomicAdd(dp + 0, v.x);
    atomicAdd(dp + 1, v.y);
    atomicAdd(dp + 2, v.z);
    atomicAdd(dp + 3, v.w);
}

// ---------- transform: (optional norm) -> matmul+bias -> LayerNorm -> ReLU --
__global__ __launch_bounds__(256) void gcn_transform(
    const float* __restrict__ w, const float* __restrict__ bias,
    const float* __restrict__ gamma, const float* __restrict__ beta,
    const float* __restrict__ degf /* may be null */,
    float* __restrict__ x, int n_nodes) {
    __shared__ float xa[F];
    __shared__ float part[2][F];
    __shared__ float wsum[4], wsq[4];

    const int tid = threadIdx.x;
    const int j  = tid & (F - 1);
    const int h2 = tid >> 7;

    float wreg[64];
    #pragma unroll
    for (int k = 0; k < 64; ++k)
        wreg[k] = w[(size_t)(h2 * 64 + k) * F + j];

    const float bj  = bias[j];
    const float gj  = gamma[j];
    const float btj = beta[j];

    for (int node = blockIdx.x; node < n_nodes; node += gridDim.x) {
        if (tid < F) {
            float v = x[(size_t)node * F + tid];
            if (degf) {
                float dg = degf[node];
                v *= (dg > 0.0f ? 1.0f / dg : 0.0f);
            }
            xa[tid] = v;
        }
        __syncthreads();

        float acc = 0.0f;
        #pragma unroll
        for (int k = 0; k < 64; ++k)
            acc = fmaf(xa[h2 * 64 + k], wreg[k], acc);
        part[h2][j] = acc;
        __syncthreads();

        float xv = 0.0f;
        if (h2 == 0) xv = part[0][j] + part[1][j] + bj;

        float s = xv, q = xv * xv;
        #pragma unroll
        for (int o = 32; o > 0; o >>= 1) {
            s += __shfl_xor(s, o);
            q += __shfl_xor(q, o);
        }
        if ((tid & 63) == 0) { wsum[tid >> 6] = s; wsq[tid >> 6] = q; }
        __syncthreads();

        if (h2 == 0) {
            float mean = (wsum[0] + wsum[1]) * (1.0f / F);
            float var  = (wsq[0] + wsq[1]) * (1.0f / F) - mean * mean;
            float rstd = rsqrtf(var + 1e-5f);
            float y = (xv - mean) * rstd * gj + btj;
            x[(size_t)node * F + j] = fmaxf(y, 0.0f);
        }
        __syncthreads();   // protect xa/part rewrite on next iteration
    }
}

extern "C" void kernel_launch(void* const* d_in, const int* in_sizes, int n_in,
                              void* d_out, int out_size, void* d_ws, size_t ws_size,
                              hipStream_t stream) {
    const float* h      = (const float*)d_in[0];
    const float* weight = (const float*)d_in[1];
    const float* bias   = (const float*)d_in[2];
    const float* gamma  = (const float*)d_in[3];
    const float* beta   = (const float*)d_in[4];
    const int*   src    = (const int*)d_in[5];
    const int*   dst    = (const int*)d_in[6];

    const int n_nodes = in_sizes[0] / F;
    const int n_edges = in_sizes[5];

    float* x = (float*)d_out;   // N x 128, ah then output in place

    // workspace layout (ints): deg[N] | cursor[N] | offs[N] | bsum[pad] | esrc[E]
    const int nscan = (n_nodes + SCANB - 1) / SCANB;
    size_t need = ((size_t)3 * n_nodes + 256 + (size_t)n_edges) * sizeof(int);

    if (ws_size >= need) {
        int* deg    = (int*)d_ws;
        int* cursor = deg + n_nodes;
        int* offs   = cursor + n_nodes;
        int* bsum   = offs + n_nodes;
        int* esrc   = bsum + 256;

        // zero deg+cursor (contiguous)
        hipMemsetAsync(deg, 0, (size_t)2 * n_nodes * sizeof(int), stream);

        k_hist<<<(n_edges + 255) / 256, 256, 0, stream>>>(dst, deg, n_edges);
        k_scan_a<<<nscan, SCANB, 0, stream>>>(deg, offs, bsum, n_nodes);
        k_scan_b<<<1, 64, 0, stream>>>(bsum, nscan);
        k_scan_c<<<nscan, SCANB, 0, stream>>>(offs, bsum, n_nodes);
        k_scatter_idx<<<(n_edges + 255) / 256, 256, 0, stream>>>(
            src, dst, offs, cursor, esrc, n_edges);
        k_gather<<<((size_t)n_nodes * 64 + 255) / 256, 256, 0, stream>>>(
            h, esrc, offs, deg, x, n_nodes);
        gcn_transform<<<4096, 256, 0, stream>>>(weight, bias, gamma, beta,
                                                nullptr, x, n_nodes);
    } else {
        // fallback: float-atomic scatter (round-1 path)
        float* degf = (float*)d_ws;
        hipMemsetAsync(d_out, 0, (size_t)n_nodes * F * sizeof(float), stream);
        hipMemsetAsync(degf, 0, (size_t)n_nodes * sizeof(float), stream);
        int total = n_edges * 32;
        gcn_scatter_atomic<<<(total + 255) / 256, 256, 0, stream>>>(
            h, src, dst, x, degf, n_edges);
        gcn_transform<<<4096, 256, 0, stream>>>(weight, bias, gamma, beta,
                                                degf, x, n_nodes);
    }
}

// Round 3
// 318.165 us; speedup vs baseline: 9.1635x; 1.3127x over previous
//
#include <hip/hip_runtime.h>

#define F 128
#define SCANB 1024

typedef __attribute__((ext_vector_type(8))) short short8;
typedef __attribute__((ext_vector_type(4))) float f32x4;

static __device__ __forceinline__ short f2bf(float f) {
    union { float f; unsigned u; } v; v.f = f;
    unsigned r = v.u + 0x7FFF + ((v.u >> 16) & 1);   // round-to-nearest-even
    return (short)(r >> 16);
}
static __device__ __forceinline__ float bf_lo(unsigned u) {
    return __builtin_bit_cast(float, u << 16);
}
static __device__ __forceinline__ float bf_hi(unsigned u) {
    return __builtin_bit_cast(float, u & 0xFFFF0000u);
}

// ---------- CSR build: histogram of dst ----------
__global__ __launch_bounds__(256) void k_hist(const int* __restrict__ dst,
                                              int* __restrict__ deg, int n_edges) {
    int e = blockIdx.x * 256 + threadIdx.x;
    if (e < n_edges) atomicAdd(&deg[dst[e]], 1);
}

// ---------- exclusive scan over deg ----------
__global__ __launch_bounds__(SCANB) void k_scan_a(const int* __restrict__ deg,
                                                  int* __restrict__ offs,
                                                  int* __restrict__ bsum, int n) {
    __shared__ int tmp[SCANB];
    int i = blockIdx.x * SCANB + threadIdx.x;
    int v = (i < n) ? deg[i] : 0;
    tmp[threadIdx.x] = v;
    __syncthreads();
    for (int off = 1; off < SCANB; off <<= 1) {
        int t = (threadIdx.x >= off) ? tmp[threadIdx.x - off] : 0;
        __syncthreads();
        tmp[threadIdx.x] += t;
        __syncthreads();
    }
    if (i < n) offs[i] = tmp[threadIdx.x] - v;
    if (threadIdx.x == SCANB - 1) bsum[blockIdx.x] = tmp[SCANB - 1];
}

__global__ void k_scan_b(int* bsum, int nb) {
    if (threadIdx.x == 0 && blockIdx.x == 0) {
        int run = 0;
        for (int b = 0; b < nb; ++b) { int t = bsum[b]; bsum[b] = run; run += t; }
    }
}

__global__ __launch_bounds__(SCANB) void k_scan_c(int* __restrict__ offs,
                                                  const int* __restrict__ bsum, int n) {
    int i = blockIdx.x * SCANB + threadIdx.x;
    if (i < n) offs[i] += bsum[blockIdx.x];
}

// ---------- scatter edge src-ids into CSR order ----------
__global__ __launch_bounds__(256) void k_scatter_idx(
    const int* __restrict__ src, const int* __restrict__ dst,
    const int* __restrict__ offs, int* __restrict__ cursor,
    int* __restrict__ esrc, int n_edges) {
    int e = blockIdx.x * 256 + threadIdx.x;
    if (e >= n_edges) return;
    int d = dst[e];
    int pos = offs[d] + atomicAdd(&cursor[d], 1);
    esrc[pos] = src[e];
}

// ---------- h (f32) -> hb (bf16 packed pairs) ----------
__global__ __launch_bounds__(256) void k_h2b(const float* __restrict__ h,
                                             unsigned* __restrict__ hb, int total8) {
    int t = blockIdx.x * 256 + threadIdx.x;
    if (t >= total8) return;
    const float4* hp = (const float4*)h;
    float4 a = hp[t * 2], b = hp[t * 2 + 1];
    uint4 o;
    o.x = ((unsigned)(unsigned short)f2bf(a.y) << 16) | (unsigned short)f2bf(a.x);
    o.y = ((unsigned)(unsigned short)f2bf(a.w) << 16) | (unsigned short)f2bf(a.z);
    o.z = ((unsigned)(unsigned short)f2bf(b.y) << 16) | (unsigned short)f2bf(b.x);
    o.w = ((unsigned)(unsigned short)f2bf(b.w) << 16) | (unsigned short)f2bf(b.z);
    ((uint4*)hb)[t] = o;
}

// ---------- gather-sum from bf16 h: one wave per node ----------
__global__ __launch_bounds__(256) void k_gather_bf16(
    const unsigned* __restrict__ hb, const int* __restrict__ esrc,
    const int* __restrict__ offs, const int* __restrict__ deg,
    float* __restrict__ x, int n_nodes) {
    int t = blockIdx.x * 256 + threadIdx.x;
    int node = t >> 6;
    int lane = t & 63;
    if (node >= n_nodes) return;
    int start = offs[node];
    int dn = deg[node];
    float ax = 0.0f, ay = 0.0f;
    int i = 0;
    for (; i + 4 <= dn; i += 4) {
        int s0 = esrc[start + i + 0], s1 = esrc[start + i + 1];
        int s2 = esrc[start + i + 2], s3 = esrc[start + i + 3];
        unsigned u0 = hb[(size_t)s0 * 64 + lane];
        unsigned u1 = hb[(size_t)s1 * 64 + lane];
        unsigned u2 = hb[(size_t)s2 * 64 + lane];
        unsigned u3 = hb[(size_t)s3 * 64 + lane];
        ax += (bf_lo(u0) + bf_lo(u1)) + (bf_lo(u2) + bf_lo(u3));
        ay += (bf_hi(u0) + bf_hi(u1)) + (bf_hi(u2) + bf_hi(u3));
    }
    for (; i < dn; ++i) {
        int s = esrc[start + i];
        unsigned u = hb[(size_t)s * 64 + lane];
        ax += bf_lo(u); ay += bf_hi(u);
    }
    float nv = dn > 0 ? 1.0f / (float)dn : 0.0f;
    ((float2*)x)[(size_t)node * 64 + lane] = make_float2(ax * nv, ay * nv);
}

// ---------- gather-sum from f32 h (fallback) ----------
__global__ __launch_bounds__(256) void k_gather_f32(
    const float* __restrict__ h, const int* __restrict__ esrc,
    const int* __restrict__ offs, const int* __restrict__ deg,
    float* __restrict__ x, int n_nodes) {
    int t = blockIdx.x * 256 + threadIdx.x;
    int node = t >> 6;
    int lane = t & 63;
    if (node >= n_nodes) return;
    int start = offs[node];
    int dn = deg[node];
    const float2* hp = (const float2*)h;
    float ax = 0.0f, ay = 0.0f;
    int i = 0;
    for (; i + 4 <= dn; i += 4) {
        int s0 = esrc[start + i + 0], s1 = esrc[start + i + 1];
        int s2 = esrc[start + i + 2], s3 = esrc[start + i + 3];
        float2 v0 = hp[(size_t)s0 * 64 + lane];
        float2 v1 = hp[(size_t)s1 * 64 + lane];
        float2 v2 = hp[(size_t)s2 * 64 + lane];
        float2 v3 = hp[(size_t)s3 * 64 + lane];
        ax += (v0.x + v1.x) + (v2.x + v3.x);
        ay += (v0.y + v1.y) + (v2.y + v3.y);
    }
    for (; i < dn; ++i) {
        int s = esrc[start + i];
        float2 v = hp[(size_t)s * 64 + lane];
        ax += v.x; ay += v.y;
    }
    float nv = dn > 0 ? 1.0f / (float)dn : 0.0f;
    ((float2*)x)[(size_t)node * 64 + lane] = make_float2(ax * nv, ay * nv);
}

// ---------- MFMA transform: x_norm @ W + bias -> LayerNorm -> ReLU ----------
// Block = 256 threads (4 waves); each wave owns 16 rows; block M-tile = 64.
// W staged transposed in LDS as bf16, padded stride 136 (bank-conflict-free).
__global__ __launch_bounds__(256) void k_transform_mfma(
    const float* __restrict__ w, const float* __restrict__ bias,
    const float* __restrict__ gamma, const float* __restrict__ beta,
    float* __restrict__ x, int n_nodes) {
    __shared__ short wt[128 * 136];   // wt[col][k]

    const int tid = threadIdx.x;
    {
        int n = tid & 127;
        for (int k = tid >> 7; k < 128; k += 2)
            wt[n * 136 + k] = f2bf(w[(size_t)k * 128 + n]);
    }
    __syncthreads();

    const int wid = tid >> 6;
    const int l   = tid & 63;
    const int lr  = l & 15;       // A-row / C-col within 16x16 tile
    const int lk  = l >> 4;       // k-subgroup / C-row group

    float bs[8], gm[8], bt[8];
    #pragma unroll
    for (int n = 0; n < 8; ++n) {
        int c = n * 16 + lr;
        bs[n] = bias[c]; gm[n] = gamma[c]; bt[n] = beta[c];
    }

    for (int base = blockIdx.x * 64; base < n_nodes; base += gridDim.x * 64) {
        const int row = base + wid * 16 + lr;
        const bool valid = row < n_nodes;

        short8 af[4];
        #pragma unroll
        for (int kk = 0; kk < 4; ++kk) {
            int k0 = kk * 32 + lk * 8;
            float4 a0{0,0,0,0}, a1{0,0,0,0};
            if (valid) {
                a0 = *(const float4*)(x + (size_t)row * F + k0);
                a1 = *(const float4*)(x + (size_t)row * F + k0 + 4);
            }
            af[kk] = short8{ f2bf(a0.x), f2bf(a0.y), f2bf(a0.z), f2bf(a0.w),
                             f2bf(a1.x), f2bf(a1.y), f2bf(a1.z), f2bf(a1.w) };
        }

        f32x4 acc[8];
        #pragma unroll
        for (int n = 0; n < 8; ++n) acc[n] = f32x4{0, 0, 0, 0};

        #pragma unroll
        for (int kk = 0; kk < 4; ++kk) {
            const int kb = kk * 32 + lk * 8;
            #pragma unroll
            for (int n = 0; n < 8; ++n) {
                short8 bfr = *(const short8*)(&wt[(n * 16 + lr) * 136 + kb]);
                acc[n] = __builtin_amdgcn_mfma_f32_16x16x32_bf16(af[kk], bfr, acc[n], 0, 0, 0);
            }
        }

        // bias + LN stats (rows = base + wid*16 + lk*4 + r, cols spread over lr&tiles)
        float s4[4] = {0,0,0,0}, q4[4] = {0,0,0,0};
        #pragma unroll
        for (int n = 0; n < 8; ++n)
            #pragma unroll
            for (int r = 0; r < 4; ++r) {
                float v = acc[n][r] + bs[n];
                acc[n][r] = v;
                s4[r] += v; q4[r] += v * v;
            }
        #pragma unroll
        for (int m = 1; m < 16; m <<= 1)
            #pragma unroll
            for (int r = 0; r < 4; ++r) {
                s4[r] += __shfl_xor(s4[r], m);
                q4[r] += __shfl_xor(q4[r], m);
            }

        #pragma unroll
        for (int r = 0; r < 4; ++r) {
            float mu   = s4[r] * (1.0f / F);
            float var  = q4[r] * (1.0f / F) - mu * mu;
            float rstd = rsqrtf(var + 1e-5f);
            int rw = base + wid * 16 + lk * 4 + r;
            if (rw < n_nodes) {
                #pragma unroll
                for (int n = 0; n < 8; ++n) {
                    float y = (acc[n][r] - mu) * rstd * gm[n] + bt[n];
                    x[(size_t)rw * F + n * 16 + lr] = fmaxf(y, 0.0f);
                }
            }
        }
    }
}

extern "C" void kernel_launch(void* const* d_in, const int* in_sizes, int n_in,
                              void* d_out, int out_size, void* d_ws, size_t ws_size,
                              hipStream_t stream) {
    const float* h      = (const float*)d_in[0];
    const float* weight = (const float*)d_in[1];
    const float* bias   = (const float*)d_in[2];
    const float* gamma  = (const float*)d_in[3];
    const float* beta   = (const float*)d_in[4];
    const int*   src    = (const int*)d_in[5];
    const int*   dst    = (const int*)d_in[6];

    const int n_nodes = in_sizes[0] / F;
    const int n_edges = in_sizes[5];

    float* x = (float*)d_out;   // N x 128: x_norm after gather, output after transform

    // ws ints: deg[N] | cursor[N] | offs[N] | bsum[256] | esrc[E] | hb[N*64 u32]
    const int nscan = (n_nodes + SCANB - 1) / SCANB;
    int* deg    = (int*)d_ws;
    int* cursor = deg + n_nodes;
    int* offs   = cursor + n_nodes;
    int* bsum   = offs + n_nodes;
    int* esrc   = bsum + 256;
    unsigned* hb = (unsigned*)(esrc + n_edges);

    size_t need_base = ((size_t)3 * n_nodes + 256 + (size_t)n_edges) * sizeof(int);
    size_t need_bf16 = need_base + (size_t)n_nodes * 64 * sizeof(unsigned);
    bool use_bf16 = ws_size >= need_bf16;

    hipMemsetAsync(deg, 0, (size_t)2 * n_nodes * sizeof(int), stream);

    if (use_bf16) {
        int total8 = n_nodes * F / 8;
        k_h2b<<<(total8 + 255) / 256, 256, 0, stream>>>(h, hb, total8);
    }
    k_hist<<<(n_edges + 255) / 256, 256, 0, stream>>>(dst, deg, n_edges);
    k_scan_a<<<nscan, SCANB, 0, stream>>>(deg, offs, bsum, n_nodes);
    k_scan_b<<<1, 64, 0, stream>>>(bsum, nscan);
    k_scan_c<<<nscan, SCANB, 0, stream>>>(offs, bsum, n_nodes);
    k_scatter_idx<<<(n_edges + 255) / 256, 256, 0, stream>>>(
        src, dst, offs, cursor, esrc, n_edges);

    int gblocks = (int)(((size_t)n_nodes * 64 + 255) / 256);
    if (use_bf16)
        k_gather_bf16<<<gblocks, 256, 0, stream>>>(hb, esrc, offs, deg, x, n_nodes);
    else
        k_gather_f32<<<gblocks, 256, 0, stream>>>(h, esrc, offs, deg, x, n_nodes);

    int tblocks = (n_nodes + 63) / 64;
    k_transform_mfma<<<tblocks, 256, 0, stream>>>(weight, bias, gamma, beta, x, n_nodes);
}